// Round 2
// baseline (613.678 us; speedup 1.0000x reference)
//
#include <hip/hip_runtime.h>
#include <stdint.h>

// Problem constants
#define BDIM   512
#define NNODE  32
#define DDIM   300
#define NREL   5
#define NEDGE  256
#define VGLOB  50000
#define VSENSE 20000

#define K1PAD  1824   // stage-1 K: 6*300=1800 padded to 57*32
#define K2PAD  320    // stage-2 K: 300 padded to 10*32
#define TILE_M 128
#define TILE_N 128
#define TILE_K 32
#define TG_GLOB  391  // ceil(50000/128)
#define TG_SENSE 157  // ceil(20000/128)

typedef __attribute__((ext_vector_type(8))) short short8;
typedef __attribute__((ext_vector_type(4))) float f32x4;

__device__ __forceinline__ unsigned short f2bf(float x) {
    unsigned int u = __float_as_uint(x);
    u += 0x7fffu + ((u >> 16) & 1u);   // RNE
    return (unsigned short)(u >> 16);
}

__device__ __forceinline__ float powi(float x, int n) {
    float r = 1.f, p = x;
    while (n) { if (n & 1) r *= p; p *= p; n >>= 1; }
    return r;
}

// ---------------------------------------------------------------------------
// K1: per-batch graph prep. Build Z[b, k] (bf16, K1PAD cols):
//   k = r*300+d, r<5 : z_r[d] = dinv[0,r]^2 * x0[d] + sum_{e: dst=0, et=r} coeff_e * x_src[d]
//   k = 5*300+d     : x0[d]          (the x @ W0 term)
//   k >= 1800       : 0
// Deterministic: edges iterated in fixed index order (graph replay re-validation).
__global__ __launch_bounds__(256) void k_prep_z(
    const float* __restrict__ x, const int* __restrict__ ei,
    const int* __restrict__ et, unsigned short* __restrict__ Zb)
{
    int b = blockIdx.x, t = threadIdx.x;
    __shared__ int   cnt[NNODE * NREL];
    __shared__ float dinv[NNODE * NREL];
    __shared__ int   ssrc[NEDGE];
    __shared__ int   sdst[NEDGE];
    __shared__ int   setp[NEDGE];
    __shared__ float z[6][DDIM];

    const int* src = ei + (size_t)b * 2 * NEDGE;
    const int* dst = src + NEDGE;
    const int* etb = et + (size_t)b * NEDGE;

    if (t < NNODE * NREL) cnt[t] = 0;
    __syncthreads();
    if (t < NEDGE) {
        int s = src[t], d = dst[t], r = etb[t];
        ssrc[t] = s; sdst[t] = d; setp[t] = r;
        atomicAdd(&cnt[d * NREL + r], 1);
    }
    __syncthreads();
    if (t < NNODE * NREL) dinv[t] = rsqrtf(1.0f + (float)cnt[t]);   // deg = 1 + count (self-loop)
    __syncthreads();

    const float* xb = x + (size_t)b * NNODE * DDIM;
    for (int d = t; d < DDIM; d += 256) {
        float x0 = xb[d];
#pragma unroll
        for (int r = 0; r < NREL; r++) { float c = dinv[r]; z[r][d] = c * c * x0; }
        z[5][d] = x0;
    }
    __syncthreads();
    // fixed-order accumulation over edges landing on node 0
    for (int e = 0; e < NEDGE; e++) {
        if (sdst[e] != 0) continue;
        int s = ssrc[e], r = setp[e];
        float coeff = dinv[s * NREL + r] * dinv[r];
        const float* xs = xb + (size_t)s * DDIM;
        // thread owns column d (d == t mod 256) for every edge -> no races
        for (int d = t; d < DDIM; d += 256) z[r][d] += coeff * xs[d];
    }
    __syncthreads();
    unsigned short* zo = Zb + (size_t)b * K1PAD;
    for (int k = t; k < K1PAD; k += 256) {
        unsigned short v = 0;
        if (k < 6 * DDIM) { int r = k / DDIM, d = k - r * DDIM; v = f2bf(z[r][d]); }
        zo[k] = v;
    }
}

// ---------------------------------------------------------------------------
// K2: stacked conv weights, transposed to B[n][k] layout (fp32, zero padded):
//   Wcb[n][k] = (n<300 && k<1800) ? (r<5 ? conv_W[r][d][n] : W0[d][n]) : 0,  k=r*300+d
// 384 rows so 3 N-tiles of 128 never read OOB.
__global__ __launch_bounds__(256) void k_prep_w(
    const float* __restrict__ convW, const float* __restrict__ W0f,
    float* __restrict__ Wcb)
{
    int idx = blockIdx.x * 256 + threadIdx.x;
    if (idx >= 384 * K1PAD) return;
    int n = idx / K1PAD, k = idx - n * K1PAD;
    float v = 0.f;
    if (n < DDIM && k < 6 * DDIM) {
        int r = k / DDIM, d = k - r * DDIM;
        v = (r < NREL) ? convW[((size_t)r * DDIM + d) * DDIM + n]
                       : W0f[(size_t)d * DDIM + n];
    }
    Wcb[idx] = v;
}

// ---------------------------------------------------------------------------
// Shared MFMA GEMM: C[m][n] = sum_k A[m][k] * B[n][k]  (A bf16 ws, B fp32 global
// converted to bf16 in-flight). 128x128 tile, 4 waves of 64x64, 16x16x32 bf16 MFMA.
// Two "segments" selected by blockIdx.x so glob+sense run in one launch.
// MODE 0: plain store      (stage-1 GEMM)
// MODE 1: softmax stats    (per-tile row max / sumexp partials)
// MODE 2: store + bias - lse[row]   (final log_softmax write)
template<int MODE>
__global__ __launch_bounds__(256) void k_gemm(
    const unsigned short* __restrict__ A, int ldk, int nk,
    int tiles0,
    const float* __restrict__ B0, int ldb0, int ksrc0, int brows0,
    const float* __restrict__ bias0, float* __restrict__ C0, long ldc0,
    int nstore0, const float* __restrict__ lse0, int tilebase0,
    const float* __restrict__ B1, int ldb1, int ksrc1, int brows1,
    const float* __restrict__ bias1, float* __restrict__ C1, long ldc1,
    int nstore1, const float* __restrict__ lse1, int tilebase1,
    float* __restrict__ pmax, float* __restrict__ psum)
{
    __shared__ __align__(16) short Alds[TILE_M * TILE_K];
    __shared__ __align__(16) short Blds[TILE_N * TILE_K];

    int t = threadIdx.x;
    int bx = blockIdx.x;
    const float *Bsrc, *bias, *lse; float* Cout;
    long ldc; int ldb, ksrc, brows, nstore, tileidx;
    if (bx < tiles0) {
        Bsrc = B0; bias = bias0; Cout = C0; lse = lse0; ldc = ldc0;
        ldb = ldb0; ksrc = ksrc0; brows = brows0; nstore = nstore0;
        tileidx = tilebase0 + bx;
    } else {
        bx -= tiles0;
        Bsrc = B1; bias = bias1; Cout = C1; lse = lse1; ldc = ldc1;
        ldb = ldb1; ksrc = ksrc1; brows = brows1; nstore = nstore1;
        tileidx = tilebase1 + bx;
    }
    int n0 = bx * TILE_N;
    int m0 = blockIdx.y * TILE_M;

    int lane = t & 63, wid = t >> 6;
    int wm = wid >> 1, wn = wid & 1;
    int l15 = lane & 15, lq = lane >> 4;

    f32x4 acc[4][4] = {};

    // A staging: 2 threads/row, 32B each
    int arow = t >> 1, acol = (t & 1) * 16;
    const unsigned short* aptr = A + (size_t)(m0 + arow) * ldk + acol;
    // B staging: 8 threads/row (dwordx4 each), 4 rows/thread
    int brow = t >> 3, bkq = (t & 7) * 4;

    int ksteps = nk / TILE_K;
    for (int kt = 0; kt < ksteps; ++kt) {
        int k0 = kt * TILE_K;
        uint4 a0 = *(const uint4*)(aptr + k0);
        uint4 a1 = *(const uint4*)(aptr + k0 + 8);
        float4 bv[4];
#pragma unroll
        for (int j = 0; j < 4; j++) {
            int row = n0 + brow + 32 * j;
            float4 v = {0.f, 0.f, 0.f, 0.f};
            if (row < brows && (k0 + bkq + 4) <= ksrc)   // ksrc%4==0 -> full or zero
                v = *(const float4*)(Bsrc + (size_t)row * ldb + k0 + bkq);
            bv[j] = v;
        }
        __syncthreads();   // prev iteration's ds_reads done before overwriting LDS
        *(uint4*)&Alds[arow * TILE_K + acol] = a0;
        *(uint4*)&Alds[arow * TILE_K + acol + 8] = a1;
#pragma unroll
        for (int j = 0; j < 4; j++) {
            unsigned int p0 = (unsigned int)f2bf(bv[j].x) | ((unsigned int)f2bf(bv[j].y) << 16);
            unsigned int p1 = (unsigned int)f2bf(bv[j].z) | ((unsigned int)f2bf(bv[j].w) << 16);
            uint2 pp; pp.x = p0; pp.y = p1;
            *(uint2*)&Blds[(brow + 32 * j) * TILE_K + bkq] = pp;
        }
        __syncthreads();
        short8 afr[4], bfr[4];
#pragma unroll
        for (int i = 0; i < 4; i++) {
            afr[i] = *(const short8*)&Alds[(wm * 64 + i * 16 + l15) * TILE_K + lq * 8];
            bfr[i] = *(const short8*)&Blds[(wn * 64 + i * 16 + l15) * TILE_K + lq * 8];
        }
#pragma unroll
        for (int mi = 0; mi < 4; mi++)
#pragma unroll
            for (int ni = 0; ni < 4; ni++)
                acc[mi][ni] = __builtin_amdgcn_mfma_f32_16x16x32_bf16(
                    afr[mi], bfr[ni], acc[mi][ni], 0, 0, 0);
    }

    if constexpr (MODE == 1) {
        __shared__ float sMax[128][2];
        __shared__ float sSum[128][2];
#pragma unroll
        for (int mi = 0; mi < 4; mi++) {
#pragma unroll
            for (int r = 0; r < 4; r++) {
                float vals[4];
                float rowmax = -3.0e38f;
#pragma unroll
                for (int ni = 0; ni < 4; ni++) {
                    int col = n0 + wn * 64 + ni * 16 + l15;
                    float v = -3.0e38f;
                    if (col < nstore) v = acc[mi][ni][r] + bias[col];
                    vals[ni] = v;
                    rowmax = fmaxf(rowmax, v);
                }
#pragma unroll
                for (int off = 1; off < 16; off <<= 1)
                    rowmax = fmaxf(rowmax, __shfl_xor(rowmax, off, 64));
                float s = 0.f;
#pragma unroll
                for (int ni = 0; ni < 4; ni++) s += __expf(vals[ni] - rowmax);
#pragma unroll
                for (int off = 1; off < 16; off <<= 1) s += __shfl_xor(s, off, 64);
                if (l15 == 0) {
                    int rl = wm * 64 + mi * 16 + lq * 4 + r;
                    sMax[rl][wn] = rowmax; sSum[rl][wn] = s;
                }
            }
        }
        __syncthreads();
        if (t < 128) {
            float ma = sMax[t][0], mb = sMax[t][1];
            float M = fmaxf(ma, mb);
            float S = sSum[t][0] * __expf(ma - M) + sSum[t][1] * __expf(mb - M);
            size_t o = (size_t)tileidx * BDIM + (m0 + t);
            pmax[o] = M; psum[o] = S;
        }
    } else {
#pragma unroll
        for (int mi = 0; mi < 4; mi++) {
            int row = m0 + wm * 64 + mi * 16 + lq * 4;
#pragma unroll
            for (int ni = 0; ni < 4; ni++) {
                int col = n0 + wn * 64 + ni * 16 + l15;
                if (col < nstore) {
#pragma unroll
                    for (int r = 0; r < 4; r++) {
                        float v = acc[mi][ni][r];
                        if constexpr (MODE == 2) v += bias[col] - lse[row + r];
                        Cout[(size_t)(row + r) * ldc + col] = v;
                    }
                }
            }
        }
    }
}

// ---------------------------------------------------------------------------
// Gate recurrence m_b = g*p_b + (1-g)*m_{b-1} as affine scan: 8 block-local
// scans (zero init) + sequential combine + fixup with (1-g)^k * m_start.
__global__ __launch_bounds__(320) void k_scan_local(
    const float* __restrict__ prop, float* __restrict__ scanA,
    const float* __restrict__ gate)
{
    int d = threadIdx.x; if (d >= 304) return;
    int blk = blockIdx.x;
    float g = gate[0], og = 1.f - g;
    float m = 0.f;
    const float* p = prop + (size_t)blk * 64 * 304 + d;
    float* o = scanA + (size_t)blk * 64 * 304 + d;
#pragma unroll
    for (int i = 0; i < 64; i++) {
        m = g * p[(size_t)i * 304] + og * m;
        o[(size_t)i * 304] = m;
    }
}

__global__ __launch_bounds__(320) void k_scan_combine(
    const float* __restrict__ scanA, const float* __restrict__ gate,
    const float* __restrict__ mem0, float* __restrict__ mstart)
{
    int d = threadIdx.x; if (d >= DDIM) return;
    float g = gate[0], og = 1.f - g;
    float c64 = powi(og, 64);
    float m = mem0[d];   // memory0 row 0
#pragma unroll
    for (int blk = 0; blk < 8; blk++) {
        mstart[blk * 304 + d] = m;
        m = scanA[(size_t)(blk * 64 + 63) * 304 + d] + c64 * m;
    }
}

__global__ __launch_bounds__(320) void k_finalize_x1(
    const float* __restrict__ scanA, const float* __restrict__ mstart,
    const float* __restrict__ gate, unsigned short* __restrict__ x1b)
{
    int b = blockIdx.x, d = threadIdx.x;
    unsigned short v = 0;
    if (d < DDIM) {
        float g = gate[0], og = 1.f - g;
        float mval = scanA[(size_t)b * 304 + d]
                   + powi(og, (b & 63) + 1) * mstart[(b >> 6) * 304 + d];
        v = f2bf(fmaxf(mval, 0.f));
    }
    if (d < K2PAD) x1b[(size_t)b * K2PAD + d] = v;   // d in [300,320) padded 0
}

// ---------------------------------------------------------------------------
// lse[b] per segment from per-tile partials (online max/sumexp merge).
__global__ __launch_bounds__(512) void k_lse(
    const float* __restrict__ pmax, const float* __restrict__ psum,
    float* __restrict__ lse)
{
    int seg = blockIdx.x, b = threadIdx.x;
    int base = seg ? TG_GLOB : 0;
    int nt = seg ? TG_SENSE : TG_GLOB;
    float M = -3.0e38f, S = 0.f;
    for (int i = 0; i < nt; i++) {
        size_t o = (size_t)(base + i) * BDIM + b;
        float m = pmax[o], s = psum[o];
        if (m > M) { S = S * __expf(M - m) + s; M = m; }
        else       { S += s * __expf(m - M); }
    }
    lse[seg * BDIM + b] = M + __logf(S);
}

// ---------------------------------------------------------------------------
extern "C" void kernel_launch(void* const* d_in, const int* in_sizes, int n_in,
                              void* d_out, int out_size, void* d_ws, size_t ws_size,
                              hipStream_t stream)
{
    (void)in_sizes; (void)n_in; (void)out_size; (void)ws_size;
    const float* x      = (const float*)d_in[0];
    const int*   ei     = (const int*)d_in[1];
    const int*   et     = (const int*)d_in[2];
    const float* convW  = (const float*)d_in[3];
    const float* W0f    = (const float*)d_in[4];
    const float* gate   = (const float*)d_in[5];
    const float* globW  = (const float*)d_in[6];
    const float* globB  = (const float*)d_in[7];
    const float* senseW = (const float*)d_in[8];
    const float* senseB = (const float*)d_in[9];
    const float* mem0   = (const float*)d_in[10];
    float* out = (float*)d_out;

    // workspace layout (total ~8.5 MB, all offsets 256B aligned)
    char* w = (char*)d_ws;
    unsigned short* Zb  = (unsigned short*)(w + 0);        // 512*1824*2 = 1867776
    float* Wcb          = (float*)(w + 1867776);           // 384*1824*4 = 2801664
    unsigned short* x1b = (unsigned short*)(w + 4669440);  // 512*320*2  = 327680
    float* prop         = (float*)(w + 4997120);           // 512*304*4  = 622592
    float* scanA        = (float*)(w + 5619712);           // 512*304*4  = 622592
    float* mstart       = (float*)(w + 6242304);           // 8*304*4    = 9728
    float* pmax         = (float*)(w + 6252032);           // 548*512*4  = 1122304
    float* psum         = (float*)(w + 7374336);           // 548*512*4  = 1122304
    float* lse          = (float*)(w + 8496640);           // 2*512*4    = 4096

    k_prep_z<<<BDIM, 256, 0, stream>>>(x, ei, et, Zb);
    k_prep_w<<<(384 * K1PAD + 255) / 256, 256, 0, stream>>>(convW, W0f, Wcb);

    // proposed0[512 x 304] = Zb[512 x 1824] . Wcb^T
    k_gemm<0><<<dim3(3, 4), 256, 0, stream>>>(Zb, K1PAD, K1PAD,
        3, Wcb, K1PAD, K1PAD, 384, nullptr, prop, 304, 304, nullptr, 0,
        nullptr, 0, 0, 0, nullptr, nullptr, 0, 0, nullptr, 0,
        nullptr, nullptr);

    k_scan_local<<<8, 320, 0, stream>>>(prop, scanA, gate);
    k_scan_combine<<<1, 320, 0, stream>>>(scanA, gate, mem0, mstart);
    k_finalize_x1<<<BDIM, 320, 0, stream>>>(scanA, mstart, gate, x1b);

    // stats pass (glob + sense fused in one launch)
    k_gemm<1><<<dim3(TG_GLOB + TG_SENSE, 4), 256, 0, stream>>>(x1b, K2PAD, K2PAD,
        TG_GLOB, globW, DDIM, DDIM, VGLOB, globB, nullptr, 0, VGLOB, nullptr, 0,
        senseW, DDIM, DDIM, VSENSE, senseB, nullptr, 0, VSENSE, nullptr, TG_GLOB,
        pmax, psum);

    k_lse<<<2, 512, 0, stream>>>(pmax, psum, lse);

    // write pass: logits + bias - lse[b]
    k_gemm<2><<<dim3(TG_GLOB + TG_SENSE, 4), 256, 0, stream>>>(x1b, K2PAD, K2PAD,
        TG_GLOB, globW, DDIM, DDIM, VGLOB, globB, out, VGLOB, VGLOB, lse, 0,
        senseW, DDIM, DDIM, VSENSE, senseB, out + (size_t)BDIM * VGLOB, VSENSE, VSENSE, lse + BDIM, 0,
        nullptr, nullptr);
}

// Round 3
// 425.014 us; speedup vs baseline: 1.4439x; 1.4439x over previous
//
#include <hip/hip_runtime.h>
#include <stdint.h>

// Problem constants
#define BDIM   512
#define NNODE  32
#define DDIM   300
#define NREL   5
#define NEDGE  256
#define VGLOB  50000
#define VSENSE 20000

#define K1PAD  1824   // stage-1 K: 6*300=1800 padded to 57*32
#define K2PAD  320    // stage-2 K: 300 padded to 10*32
#define TILE_M 128
#define TILE_N 128
#define TILE_K 32
#define TG_GLOB  391  // ceil(50000/128)
#define TG_SENSE 157  // ceil(20000/128)
#define GROWS  50048  // 391*128 padded rows
#define SROWS  20096  // 157*128
#define WROWS  70144  // GROWS+SROWS
#define NCHUNK 3      // stage-1 split-K chunks
#define KCH    19     // k-steps per chunk (3*19 = 57)

typedef __attribute__((ext_vector_type(8))) short short8;
typedef __attribute__((ext_vector_type(4))) float f32x4;

__device__ __forceinline__ unsigned short f2bf(float x) {
    unsigned int u = __float_as_uint(x);
    u += 0x7fffu + ((u >> 16) & 1u);   // RNE
    return (unsigned short)(u >> 16);
}

__device__ __forceinline__ float powi(float x, int n) {
    float r = 1.f, p = x;
    while (n) { if (n & 1) r *= p; p *= p; n >>= 1; }
    return r;
}

// ---------------------------------------------------------------------------
// K1: per-batch graph prep. Build Z[b, k] (bf16, K1PAD cols). Fixed-order
// edge accumulation (deterministic across graph replays).
__global__ __launch_bounds__(256) void k_prep_z(
    const float* __restrict__ x, const int* __restrict__ ei,
    const int* __restrict__ et, unsigned short* __restrict__ Zb)
{
    int b = blockIdx.x, t = threadIdx.x;
    __shared__ int   cnt[NNODE * NREL];
    __shared__ float dinv[NNODE * NREL];
    __shared__ int   ssrc[NEDGE];
    __shared__ int   sdst[NEDGE];
    __shared__ int   setp[NEDGE];
    __shared__ float z[6][DDIM];

    const int* src = ei + (size_t)b * 2 * NEDGE;
    const int* dst = src + NEDGE;
    const int* etb = et + (size_t)b * NEDGE;

    if (t < NNODE * NREL) cnt[t] = 0;
    __syncthreads();
    if (t < NEDGE) {
        int s = src[t], d = dst[t], r = etb[t];
        ssrc[t] = s; sdst[t] = d; setp[t] = r;
        atomicAdd(&cnt[d * NREL + r], 1);
    }
    __syncthreads();
    if (t < NNODE * NREL) dinv[t] = rsqrtf(1.0f + (float)cnt[t]);
    __syncthreads();

    const float* xb = x + (size_t)b * NNODE * DDIM;
    for (int d = t; d < DDIM; d += 256) {
        float x0 = xb[d];
#pragma unroll
        for (int r = 0; r < NREL; r++) { float c = dinv[r]; z[r][d] = c * c * x0; }
        z[5][d] = x0;
    }
    __syncthreads();
    for (int e = 0; e < NEDGE; e++) {
        if (sdst[e] != 0) continue;
        int s = ssrc[e], r = setp[e];
        float coeff = dinv[s * NREL + r] * dinv[r];
        const float* xs = xb + (size_t)s * DDIM;
        for (int d = t; d < DDIM; d += 256) z[r][d] += coeff * xs[d];
    }
    __syncthreads();
    unsigned short* zo = Zb + (size_t)b * K1PAD;
    for (int k = t; k < K1PAD; k += 256) {
        unsigned short v = 0;
        if (k < 6 * DDIM) { int r = k / DDIM, d = k - r * DDIM; v = f2bf(z[r][d]); }
        zo[k] = v;
    }
}

// ---------------------------------------------------------------------------
// K2: stacked conv weights -> bf16 B[n][k], zero padded; 384 rows x 1824.
__global__ __launch_bounds__(256) void k_prep_w(
    const float* __restrict__ convW, const float* __restrict__ W0f,
    unsigned short* __restrict__ Wcb)
{
    int idx = blockIdx.x * 256 + threadIdx.x;
    if (idx >= 384 * K1PAD) return;
    int n = idx / K1PAD, k = idx - n * K1PAD;
    float v = 0.f;
    if (n < DDIM && k < 6 * DDIM) {
        int r = k / DDIM, d = k - r * DDIM;
        v = (r < NREL) ? convW[((size_t)r * DDIM + d) * DDIM + n]
                       : W0f[(size_t)d * DDIM + n];
    }
    Wcb[idx] = f2bf(v);
}

// ---------------------------------------------------------------------------
// Convert glob_W + sense_W fp32 [V x 300] -> bf16 [WROWS x 320], rows and K
// zero-padded so the GEMM B path needs no bounds checks.
__global__ __launch_bounds__(256) void k_conv_w2(
    const float* __restrict__ globW, const float* __restrict__ senseW,
    unsigned short* __restrict__ Wgb)
{
    int idx = blockIdx.x * 256 + threadIdx.x;      // WROWS*80 threads
    int row = idx / 80, kq = (idx - row * 80) * 4;
    unsigned int p0 = 0, p1 = 0;
    if (kq < DDIM) {
        const float* srcp = nullptr;
        if (row < GROWS) { if (row < VGLOB) srcp = globW + (size_t)row * DDIM; }
        else { int sr = row - GROWS; if (sr < VSENSE) srcp = senseW + (size_t)sr * DDIM; }
        if (srcp) {
            float4 v = *(const float4*)(srcp + kq);
            p0 = (unsigned int)f2bf(v.x) | ((unsigned int)f2bf(v.y) << 16);
            p1 = (unsigned int)f2bf(v.z) | ((unsigned int)f2bf(v.w) << 16);
        }
    }
    uint2 pp; pp.x = p0; pp.y = p1;
    *(uint2*)(Wgb + (size_t)row * K2PAD + kq) = pp;
}

// ---------------------------------------------------------------------------
// MFMA GEMM: C[m][n] = sum_k A[m][k]*B[n][k]. A bf16. B bf16 (BF16B) or fp32
// converted in-flight (fallback). 128x128 tile, 4 waves, 16x16x32 bf16 MFMA.
// MODE 0: plain store (+split-K via blockIdx.z, partial buffers)
// MODE 1: softmax stats (per-tile row max / sumexp partials)
// MODE 2: store + bias - lse[row]
template<int MODE, bool BF16B>
__global__ __launch_bounds__(256) void k_gemm(
    const unsigned short* __restrict__ A, int ldk, int nk, int kchunk,
    int tiles0,
    const void* __restrict__ B0, int ldb0, int ksrc0, int brows0,
    const float* __restrict__ bias0, float* __restrict__ C0, long ldc0,
    int nstore0, const float* __restrict__ lse0, int tilebase0,
    const void* __restrict__ B1, int ldb1, int ksrc1, int brows1,
    const float* __restrict__ bias1, float* __restrict__ C1, long ldc1,
    int nstore1, const float* __restrict__ lse1, int tilebase1,
    float* __restrict__ pmax, float* __restrict__ psum)
{
    __shared__ __align__(16) short Alds[TILE_M * TILE_K];
    __shared__ __align__(16) short Blds[TILE_N * TILE_K];

    int t = threadIdx.x;
    int bx = blockIdx.x;
    const void* Bsrc; const float *bias, *lse; float* Cout;
    long ldc; int ldb, ksrc, brows, nstore, tileidx;
    if (bx < tiles0) {
        Bsrc = B0; bias = bias0; Cout = C0; lse = lse0; ldc = ldc0;
        ldb = ldb0; ksrc = ksrc0; brows = brows0; nstore = nstore0;
        tileidx = tilebase0 + bx;
    } else {
        bx -= tiles0;
        Bsrc = B1; bias = bias1; Cout = C1; lse = lse1; ldc = ldc1;
        ldb = ldb1; ksrc = ksrc1; brows = brows1; nstore = nstore1;
        tileidx = tilebase1 + bx;
    }
    int n0 = bx * TILE_N;
    int m0 = blockIdx.y * TILE_M;

    int kt_lo = 0, kt_hi = nk / TILE_K;
    if constexpr (MODE == 0) {
        if (kchunk > 0) {
            kt_lo = blockIdx.z * kchunk;
            int hi = kt_lo + kchunk;
            if (hi < kt_hi) kt_hi = hi;
            Cout += (size_t)blockIdx.z * (BDIM * 304);
        }
    }

    int lane = t & 63, wid = t >> 6;
    int wm = wid >> 1, wn = wid & 1;
    int l15 = lane & 15, lq = lane >> 4;

    f32x4 acc[4][4] = {};

    // A staging: 2 threads/row, 32B each
    int arow = t >> 1, acol = (t & 1) * 16;
    const unsigned short* aptr = A + (size_t)(m0 + arow) * ldk + acol;
    // B staging (bf16): 4 threads/row, 16B; two 64-row halves
    int brow4 = t >> 2, bk8 = (t & 3) * 8;
    // B staging (fp32): 8 threads/row (float4), 4 row-groups
    int brow = t >> 3, bkq = (t & 7) * 4;

    for (int kt = kt_lo; kt < kt_hi; ++kt) {
        int k0 = kt * TILE_K;
        uint4 a0 = *(const uint4*)(aptr + k0);
        uint4 a1 = *(const uint4*)(aptr + k0 + 8);
        if constexpr (BF16B) {
            const unsigned short* bb = (const unsigned short*)Bsrc;
            uint4 b0 = *(const uint4*)(bb + (size_t)(n0 + brow4) * ldb + k0 + bk8);
            uint4 b1 = *(const uint4*)(bb + (size_t)(n0 + 64 + brow4) * ldb + k0 + bk8);
            __syncthreads();
            *(uint4*)&Alds[arow * TILE_K + acol] = a0;
            *(uint4*)&Alds[arow * TILE_K + acol + 8] = a1;
            *(uint4*)&Blds[brow4 * TILE_K + bk8] = b0;
            *(uint4*)&Blds[(64 + brow4) * TILE_K + bk8] = b1;
        } else {
            const float* bf = (const float*)Bsrc;
            float4 bv[4];
#pragma unroll
            for (int j = 0; j < 4; j++) {
                int row = n0 + brow + 32 * j;
                float4 v = {0.f, 0.f, 0.f, 0.f};
                if (row < brows && (k0 + bkq + 4) <= ksrc)
                    v = *(const float4*)(bf + (size_t)row * ldb + k0 + bkq);
                bv[j] = v;
            }
            __syncthreads();
            *(uint4*)&Alds[arow * TILE_K + acol] = a0;
            *(uint4*)&Alds[arow * TILE_K + acol + 8] = a1;
#pragma unroll
            for (int j = 0; j < 4; j++) {
                unsigned int p0 = (unsigned int)f2bf(bv[j].x) | ((unsigned int)f2bf(bv[j].y) << 16);
                unsigned int p1 = (unsigned int)f2bf(bv[j].z) | ((unsigned int)f2bf(bv[j].w) << 16);
                uint2 pp; pp.x = p0; pp.y = p1;
                *(uint2*)&Blds[(brow + 32 * j) * TILE_K + bkq] = pp;
            }
        }
        __syncthreads();
        short8 afr[4], bfr[4];
#pragma unroll
        for (int i = 0; i < 4; i++) {
            afr[i] = *(const short8*)&Alds[(wm * 64 + i * 16 + l15) * TILE_K + lq * 8];
            bfr[i] = *(const short8*)&Blds[(wn * 64 + i * 16 + l15) * TILE_K + lq * 8];
        }
#pragma unroll
        for (int mi = 0; mi < 4; mi++)
#pragma unroll
            for (int ni = 0; ni < 4; ni++)
                acc[mi][ni] = __builtin_amdgcn_mfma_f32_16x16x32_bf16(
                    afr[mi], bfr[ni], acc[mi][ni], 0, 0, 0);
    }

    if constexpr (MODE == 1) {
        __shared__ float sMax[128][2];
        __shared__ float sSum[128][2];
#pragma unroll
        for (int mi = 0; mi < 4; mi++) {
#pragma unroll
            for (int r = 0; r < 4; r++) {
                float vals[4];
                float rowmax = -3.0e38f;
#pragma unroll
                for (int ni = 0; ni < 4; ni++) {
                    int col = n0 + wn * 64 + ni * 16 + l15;
                    float v = -3.0e38f;
                    if (col < nstore) v = acc[mi][ni][r] + bias[col];
                    vals[ni] = v;
                    rowmax = fmaxf(rowmax, v);
                }
#pragma unroll
                for (int off = 1; off < 16; off <<= 1)
                    rowmax = fmaxf(rowmax, __shfl_xor(rowmax, off, 64));
                float s = 0.f;
#pragma unroll
                for (int ni = 0; ni < 4; ni++) s += __expf(vals[ni] - rowmax);
#pragma unroll
                for (int off = 1; off < 16; off <<= 1) s += __shfl_xor(s, off, 64);
                if (l15 == 0) {
                    int rl = wm * 64 + mi * 16 + lq * 4 + r;
                    sMax[rl][wn] = rowmax; sSum[rl][wn] = s;
                }
            }
        }
        __syncthreads();
        if (t < 128) {
            float ma = sMax[t][0], mb = sMax[t][1];
            float M = fmaxf(ma, mb);
            float S = sSum[t][0] * __expf(ma - M) + sSum[t][1] * __expf(mb - M);
            size_t o = (size_t)tileidx * BDIM + (m0 + t);
            pmax[o] = M; psum[o] = S;
        }
    } else {
#pragma unroll
        for (int mi = 0; mi < 4; mi++) {
            int row = m0 + wm * 64 + mi * 16 + lq * 4;
#pragma unroll
            for (int ni = 0; ni < 4; ni++) {
                int col = n0 + wn * 64 + ni * 16 + l15;
                if (col < nstore) {
#pragma unroll
                    for (int r = 0; r < 4; r++) {
                        float v = acc[mi][ni][r];
                        if constexpr (MODE == 2) v += bias[col] - lse[row + r];
                        Cout[(size_t)(row + r) * ldc + col] = v;
                    }
                }
            }
        }
    }
}

// ---------------------------------------------------------------------------
// Gate recurrence as affine scan; sums NCHUNK split-K partials on the fly.
__global__ __launch_bounds__(320) void k_scan_local(
    const float* __restrict__ prop, float* __restrict__ scanA,
    const float* __restrict__ gate)
{
    int d = threadIdx.x; if (d >= 304) return;
    int blk = blockIdx.x;
    float g = gate[0], og = 1.f - g;
    float m = 0.f;
    const float* p0 = prop + (size_t)blk * 64 * 304 + d;
    const float* p1 = p0 + (size_t)BDIM * 304;
    const float* p2 = p1 + (size_t)BDIM * 304;
    float* o = scanA + (size_t)blk * 64 * 304 + d;
#pragma unroll
    for (int i = 0; i < 64; i++) {
        size_t off = (size_t)i * 304;
        float pv = p0[off] + p1[off] + p2[off];
        m = g * pv + og * m;
        o[off] = m;
    }
}

__global__ __launch_bounds__(320) void k_scan_combine(
    const float* __restrict__ scanA, const float* __restrict__ gate,
    const float* __restrict__ mem0, float* __restrict__ mstart)
{
    int d = threadIdx.x; if (d >= DDIM) return;
    float g = gate[0], og = 1.f - g;
    float c64 = powi(og, 64);
    float m = mem0[d];
#pragma unroll
    for (int blk = 0; blk < 8; blk++) {
        mstart[blk * 304 + d] = m;
        m = scanA[(size_t)(blk * 64 + 63) * 304 + d] + c64 * m;
    }
}

__global__ __launch_bounds__(320) void k_finalize_x1(
    const float* __restrict__ scanA, const float* __restrict__ mstart,
    const float* __restrict__ gate, unsigned short* __restrict__ x1b)
{
    int b = blockIdx.x, d = threadIdx.x;
    unsigned short v = 0;
    if (d < DDIM) {
        float g = gate[0], og = 1.f - g;
        float mval = scanA[(size_t)b * 304 + d]
                   + powi(og, (b & 63) + 1) * mstart[(b >> 6) * 304 + d];
        v = f2bf(fmaxf(mval, 0.f));
    }
    if (d < K2PAD) x1b[(size_t)b * K2PAD + d] = v;
}

// ---------------------------------------------------------------------------
// Parallel lse: one block per (b, seg); thread-local online merge -> wave
// shuffle merge -> cross-wave LDS merge.
__global__ __launch_bounds__(256) void k_lse_par(
    const float* __restrict__ pmax, const float* __restrict__ psum,
    float* __restrict__ lse)
{
    int b = blockIdx.x, seg = blockIdx.y, t = threadIdx.x;
    int base = seg ? TG_GLOB : 0;
    int nt = seg ? TG_SENSE : TG_GLOB;
    float M = -3.0e38f, S = 0.f;
    for (int i = t; i < nt; i += 256) {
        size_t o = (size_t)(base + i) * BDIM + b;
        float m = pmax[o], s = psum[o];
        if (m > M) { S = S * __expf(M - m) + s; M = m; }
        else       { S += s * __expf(m - M); }
    }
#pragma unroll
    for (int off = 1; off < 64; off <<= 1) {
        float Mo = __shfl_xor(M, off, 64), So = __shfl_xor(S, off, 64);
        float Mn = fmaxf(M, Mo);
        S = S * __expf(M - Mn) + So * __expf(Mo - Mn);
        M = Mn;
    }
    __shared__ float sM[4], sS[4];
    int lane = t & 63, wid = t >> 6;
    if (lane == 0) { sM[wid] = M; sS[wid] = S; }
    __syncthreads();
    if (t == 0) {
        M = sM[0]; S = sS[0];
#pragma unroll
        for (int w = 1; w < 4; w++) {
            float Mo = sM[w], So = sS[w];
            float Mn = fmaxf(M, Mo);
            S = S * __expf(M - Mn) + So * __expf(Mo - Mn);
            M = Mn;
        }
        lse[seg * BDIM + b] = M + __logf(S);
    }
}

// ---------------------------------------------------------------------------
extern "C" void kernel_launch(void* const* d_in, const int* in_sizes, int n_in,
                              void* d_out, int out_size, void* d_ws, size_t ws_size,
                              hipStream_t stream)
{
    (void)in_sizes; (void)n_in; (void)out_size;
    const float* x      = (const float*)d_in[0];
    const int*   ei     = (const int*)d_in[1];
    const int*   et     = (const int*)d_in[2];
    const float* convW  = (const float*)d_in[3];
    const float* W0f    = (const float*)d_in[4];
    const float* gate   = (const float*)d_in[5];
    const float* globW  = (const float*)d_in[6];
    const float* globB  = (const float*)d_in[7];
    const float* senseW = (const float*)d_in[8];
    const float* senseB = (const float*)d_in[9];
    const float* mem0   = (const float*)d_in[10];
    float* out = (float*)d_out;

    // workspace layout (base <= 8.35 MB; bf16 weights optional above that)
    char* w = (char*)d_ws;
    unsigned short* Zb  = (unsigned short*)(w + 0);        // 512*1824*2 = 1867776
    unsigned short* Wcb = (unsigned short*)(w + 1867776);  // 384*1824*2 = 1400832
    unsigned short* x1b = (unsigned short*)(w + 3268608);  // 512*320*2  = 327680
    float* prop         = (float*)(w + 3596288);           // 3*512*304*4= 1867776
    float* scanA        = (float*)(w + 5464064);           // 512*304*4  = 622592
    float* mstart       = (float*)(w + 6086656);           // 8*304*4    = 9728
    float* pmax         = (float*)(w + 6096384);           // 548*512*4  = 1122304
    float* psum         = (float*)(w + 7218688);           // 548*512*4  = 1122304
    float* lse          = (float*)(w + 8340992);           // 2*512*4    = 4096
    unsigned short* Wgb = (unsigned short*)(w + 8345088);  // 70144*320*2= 44892160
    const size_t WS_NEED_BIG = 8345088 + (size_t)WROWS * K2PAD * 2;  // ~53.2 MB
    bool bigws = ws_size >= WS_NEED_BIG;

    k_prep_z<<<BDIM, 256, 0, stream>>>(x, ei, et, Zb);
    k_prep_w<<<(384 * K1PAD + 255) / 256, 256, 0, stream>>>(convW, W0f, Wcb);
    if (bigws)
        k_conv_w2<<<(WROWS * 80) / 256, 256, 0, stream>>>(globW, senseW, Wgb);

    // stage-1: prop[z][512 x 304] partials = Zb . Wcb^T (split-K, 36 blocks)
    k_gemm<0, true><<<dim3(3, 4, NCHUNK), 256, 0, stream>>>(Zb, K1PAD, K1PAD, KCH,
        3, Wcb, K1PAD, K1PAD, 384, nullptr, prop, 304, 304, nullptr, 0,
        nullptr, 0, 0, 0, nullptr, nullptr, 0, 0, nullptr, 0,
        nullptr, nullptr);

    k_scan_local<<<8, 320, 0, stream>>>(prop, scanA, gate);
    k_scan_combine<<<1, 320, 0, stream>>>(scanA, gate, mem0, mstart);
    k_finalize_x1<<<BDIM, 320, 0, stream>>>(scanA, mstart, gate, x1b);

    if (bigws) {
        const unsigned short* WgbS = Wgb + (size_t)GROWS * K2PAD;
        k_gemm<1, true><<<dim3(TG_GLOB + TG_SENSE, 4), 256, 0, stream>>>(x1b, K2PAD, K2PAD, 0,
            TG_GLOB, Wgb, K2PAD, K2PAD, GROWS, globB, nullptr, 0, VGLOB, nullptr, 0,
            WgbS, K2PAD, K2PAD, SROWS, senseB, nullptr, 0, VSENSE, nullptr, TG_GLOB,
            pmax, psum);
        k_lse_par<<<dim3(BDIM, 2), 256, 0, stream>>>(pmax, psum, lse);
        k_gemm<2, true><<<dim3(TG_GLOB + TG_SENSE, 4), 256, 0, stream>>>(x1b, K2PAD, K2PAD, 0,
            TG_GLOB, Wgb, K2PAD, K2PAD, GROWS, globB, out, VGLOB, VGLOB, lse, 0,
            WgbS, K2PAD, K2PAD, SROWS, senseB, out + (size_t)BDIM * VGLOB, VSENSE, VSENSE, lse + BDIM, 0,
            nullptr, nullptr);
    } else {
        k_gemm<1, false><<<dim3(TG_GLOB + TG_SENSE, 4), 256, 0, stream>>>(x1b, K2PAD, K2PAD, 0,
            TG_GLOB, globW, DDIM, DDIM, VGLOB, globB, nullptr, 0, VGLOB, nullptr, 0,
            senseW, DDIM, DDIM, VSENSE, senseB, nullptr, 0, VSENSE, nullptr, TG_GLOB,
            pmax, psum);
        k_lse_par<<<dim3(BDIM, 2), 256, 0, stream>>>(pmax, psum, lse);
        k_gemm<2, false><<<dim3(TG_GLOB + TG_SENSE, 4), 256, 0, stream>>>(x1b, K2PAD, K2PAD, 0,
            TG_GLOB, globW, DDIM, DDIM, VGLOB, globB, out, VGLOB, VGLOB, lse, 0,
            senseW, DDIM, DDIM, VSENSE, senseB, out + (size_t)BDIM * VGLOB, VSENSE, VSENSE, lse + BDIM, 0,
            nullptr, nullptr);
    }
}